// Round 7
// baseline (962.917 us; speedup 1.0000x reference)
//
#include <hip/hip_runtime.h>
#include <hip/hip_bf16.h>

#define NV 1000000
#define CI 32
#define CO 64
#define KK 9
#define NG (NV / 16)          // 62500 voxel-groups of 16 (exact)
#define EPSV 1e-5f

typedef __bf16 bf16x8 __attribute__((ext_vector_type(8)));
typedef __bf16 bf16x4 __attribute__((ext_vector_type(4)));
typedef float  f32x4  __attribute__((ext_vector_type(4)));

__device__ __forceinline__ f32x4 mfma16(bf16x8 a, bf16x8 b, f32x4 c) {
    // D[16x16] = A[16x32] * B[32x16] + C
    // A: row=lane&15, k=(lane>>4)*8+j ; B: col=lane&15, k=(lane>>4)*8+j
    // D: col=lane&15, row=(lane>>4)*4+reg   [learn_hip m89 verified]
    // A and B fragments are indexed IDENTICALLY, so swapping the operand
    // vectors computes the transposed product with the same register data.
    return __builtin_amdgcn_mfma_f32_16x16x32_bf16(a, b, c, 0, 0, 0);
}

__device__ __forceinline__ float xredseg(float v) {   // sum over lane{+16,+32}
    v += __shfl_xor(v, 16, 64);
    v += __shfl_xor(v, 32, 64);
    return v;
}
__device__ __forceinline__ float xred16(float v) {    // sum over r=lane&15
    v += __shfl_xor(v, 1, 64);
    v += __shfl_xor(v, 2, 64);
    v += __shfl_xor(v, 4, 64);
    v += __shfl_xor(v, 8, 64);
    return v;
}

// ---------------- prep: transpose weights to [k][co][ci] bf16 ----------------
__global__ void k_prep_w(const float* __restrict__ W1, const float* __restrict__ W2,
                         const float* __restrict__ Wd,
                         __bf16* __restrict__ W1T, __bf16* __restrict__ W2T,
                         __bf16* __restrict__ WdT) {
    int i = blockIdx.x * blockDim.x + threadIdx.x;
    const int n1 = KK * CO * CI;      // 18432
    const int n2 = KK * CO * CO;      // 36864
    const int nd = CO * CI;           // 2048
    if (i < n1) {
        int k = i / (CO * CI), r = i % (CO * CI), co = r / CI, ci = r % CI;
        W1T[i] = (__bf16)W1[(k * CI + ci) * CO + co];
    } else if (i < n1 + n2) {
        int j = i - n1;
        int k = j / (CO * CO), r = j % (CO * CO), co = r / CO, ci = r % CO;
        W2T[j] = (__bf16)W2[(k * CO + ci) * CO + co];
    } else if (i < n1 + n2 + nd) {
        int j = i - n1 - n2;
        int co = j / CI, ci = j % CI;
        WdT[j] = (__bf16)Wd[ci * CO + co];
    }
}

// ---------------- prep: x fp32 -> bf16 ----------------
__global__ void k_prep_x(const float* __restrict__ x, __bf16* __restrict__ xb) {
    int i = blockIdx.x * blockDim.x + threadIdx.x;   // one thread per 8 elems
    const float4* px = (const float4*)x + 2 * (size_t)i;
    float4 u = px[0], v = px[1];
    bf16x8 o;
    o[0] = (__bf16)u.x; o[1] = (__bf16)u.y; o[2] = (__bf16)u.z; o[3] = (__bf16)u.w;
    o[4] = (__bf16)v.x; o[5] = (__bf16)v.y; o[6] = (__bf16)v.z; o[7] = (__bf16)v.w;
    *((bf16x8*)xb + i) = o;
}

// ---------------- conv1: reg-double-buffered gather-MFMA, W1 in LDS ----------
// Operand-SWAPPED main MFMA: lane (r,seg) holds 4 consecutive channels
// (t*16+seg*4+rr) of voxel vb+r -> y1b stores are 4x 8B contiguous chunks.
// Stores are NONTEMPORAL: the write stream must not evict xb from L2/L3
// (dropping nt in round 6 doubled conv1's latency — round-2 lesson).
__global__ __launch_bounds__(256, 2) void k_conv1(
    const __bf16* __restrict__ xb, const int* __restrict__ nbr,
    const __bf16* __restrict__ W1T, const __bf16* __restrict__ WdT,
    __bf16* __restrict__ y1b, float* __restrict__ stats) {
    __shared__ __align__(16) char w1smem[KK * CO * CI * 2];   // 36864 B

    const int lane = threadIdx.x & 63;
    const int w    = threadIdx.x >> 6;
    const int r    = lane & 15;
    const int seg  = lane >> 4;

    // stage W1T -> LDS, linear copy: 2304 16B-chunks, 256 threads x 9
#pragma unroll
    for (int j = 0; j < 9; j++) {
        const __bf16* srcp = W1T + (size_t)(j * 256 + threadIdx.x) * 8;
        __builtin_amdgcn_global_load_lds(
            (const __attribute__((address_space(1))) void*)srcp,
            (__attribute__((address_space(3))) void*)(w1smem + j * 4096 + w * 1024),
            16, 0, 0);
    }
    __syncthreads();

    bf16x8 wd[4];
#pragma unroll
    for (int t = 0; t < 4; t++)
        wd[t] = *(const bf16x8*)(WdT + (size_t)(t * 16 + r) * CI + seg * 8);

    float ps1[4][4], pq1[4][4];
#pragma unroll
    for (int t = 0; t < 4; t++)
#pragma unroll
        for (int rr = 0; rr < 4; rr++) { ps1[t][rr] = 0.f; pq1[t][rr] = 0.f; }
    float psd[4] = {0.f,0.f,0.f,0.f}, pqd[4] = {0.f,0.f,0.f,0.f};

    const int slot   = blockIdx.x * 4 + w;
    const int stride = gridDim.x * 4;
    const f32x4 z = {0.f, 0.f, 0.f, 0.f};

    auto loadIdx = [&](int (&idx)[KK], int tile) {
        const int* nb = nbr + (size_t)(tile * 16 + r) * KK;
#pragma unroll
        for (int k = 0; k < KK; k++) idx[k] = nb[k];
    };
    auto gather9 = [&](bf16x8 (&g)[KK], const int (&idx)[KK]) {
#pragma unroll
        for (int k = 0; k < KK; k++)
            g[k] = *(const bf16x8*)(xb + (size_t)idx[k] * CI + seg * 8);
    };
    auto loadAd = [&](int tile) {
        return *(const bf16x8*)(xb + (size_t)(tile * 16 + r) * CI + seg * 8);
    };
    auto compute = [&](int tile, const bf16x8 (&g)[KK], bf16x8 ad) {
        int w1off = 0;
        asm volatile("" : "+v"(w1off));        // defeat cross-iteration hoisting
        const __bf16* wb = (const __bf16*)w1smem + w1off;

        f32x4 acc[4]  = {z, z, z, z};
        f32x4 accd[4] = {z, z, z, z};
#pragma unroll
        for (int t = 0; t < 4; t++) accd[t] = mfma16(ad, wd[t], accd[t]);  // old order
#pragma unroll
        for (int k = 0; k < KK; k++) {
#pragma unroll
            for (int t = 0; t < 4; t++) {
                bf16x8 b = *(const bf16x8*)(wb + k * 2048 + t * 512 + r * 32 + seg * 8);
                acc[t] = mfma16(b, g[k], acc[t]);   // SWAPPED -> transposed D
            }
        }

        const int vb = tile * 16;
#pragma unroll
        for (int t = 0; t < 4; t++) {
            bf16x4 o;
#pragma unroll
            for (int rr = 0; rr < 4; rr++) {
                float val = acc[t][rr];              // y1[vb+r][t*16+seg*4+rr]
                o[rr] = (__bf16)val;
                ps1[t][rr] += val; pq1[t][rr] += val * val;
                float dv = accd[t][rr];              // dense: ch t*16+r, row seg*4+rr
                psd[t] += dv; pqd[t] += dv * dv;
            }
            __builtin_nontemporal_store(
                o, (bf16x4*)(y1b + (size_t)(vb + r) * CO + t * 16 + seg * 4));
        }
    };

    int idx0[KK], idx1[KK];
    bf16x8 g0[KK], g1[KK];
    bf16x8 ad0, ad1;

    int it = slot;                    // slot < 3072 <= NG always
    loadIdx(idx0, it);
    gather9(g0, idx0); ad0 = loadAd(it);
    int itn = it + stride;
    bool have = (itn < NG);
    if (have) loadIdx(idx1, itn);

    while (true) {
        if (have) {
            gather9(g1, idx1); ad1 = loadAd(itn);
            int it2 = itn + stride;
            if (it2 < NG) loadIdx(idx0, it2);
        }
        compute(it, g0, ad0);
        if (!have) break;
        it = itn; itn = it + stride; have = (itn < NG);

        if (have) {
            gather9(g0, idx0); ad0 = loadAd(itn);
            int it2 = itn + stride;
            if (it2 < NG) loadIdx(idx1, it2);
        }
        compute(it, g1, ad1);
        if (!have) break;
        it = itn; itn = it + stride; have = (itn < NG);
    }

    // ---- y1 stats: channel = t*16 + seg*4 + rr; sum over r (lanes 1,2,4,8) ----
#pragma unroll
    for (int t = 0; t < 4; t++)
#pragma unroll
        for (int rr = 0; rr < 4; rr++) {
            ps1[t][rr] = xred16(ps1[t][rr]);
            pq1[t][rr] = xred16(pq1[t][rr]);
        }
    if (r == 0) {
#pragma unroll
        for (int t = 0; t < 4; t++)
#pragma unroll
            for (int rr = 0; rr < 4; rr++) {
                int ch = t * 16 + seg * 4 + rr;
                atomicAdd(&stats[0 * 64 + ch], ps1[t][rr]);
                atomicAdd(&stats[1 * 64 + ch], pq1[t][rr]);
            }
    }
    // ---- dense stats: old mapping (channel = t*16 + r), sum over seg ----
#pragma unroll
    for (int t = 0; t < 4; t++) { psd[t] = xredseg(psd[t]); pqd[t] = xredseg(pqd[t]); }
    if (lane < 16) {
#pragma unroll
        for (int t = 0; t < 4; t++) {
            atomicAdd(&stats[2 * 64 + t * 16 + lane], psd[t]);
            atomicAdd(&stats[3 * 64 + t * 16 + lane], pqd[t]);
        }
    }
}

// ---------------- conv2: reg-staged gather, BN1+ReLU once at staging ----------
// Compute MFMAs operand-swapped -> lane (r,seg) holds channels w*32+t2*16+seg*4+rr
// of voxel vb+r -> y2 stored as contiguous 8B bf16 chunks (BF16OUT) or 16B f32x4
// (fallback, in d_out). All output stores NONTEMPORAL (protect y1b residency).
#define TILE_B (16 * KK * 128)     // 18432 B per buffer

template <bool BF16OUT>
__global__ __launch_bounds__(128, 2) void k_conv2(
    const __bf16* __restrict__ h1b, const int* __restrict__ nbr,
    const __bf16* __restrict__ W2T, const float* __restrict__ g1,
    const float* __restrict__ b1,
    __bf16* __restrict__ y2b, float* __restrict__ y2f,
    float* __restrict__ stats) {
    __shared__ __align__(16) char smem[2][TILE_B];   // 36864 B -> 4 blocks/CU

    const int lane = threadIdx.x & 63;
    const int w    = threadIdx.x >> 6;      // 0..1 = co-half
    const int r    = lane & 15;
    const int seg  = lane >> 4;
    const int p    = lane & 7;              // staging channel-chunk (static)

    bf16x8 w2[KK][2][2];                    // [k][t2][s]
#pragma unroll
    for (int k = 0; k < KK; k++)
#pragma unroll
        for (int t2 = 0; t2 < 2; t2++)
#pragma unroll
            for (int s = 0; s < 2; s++) {
                int co = w * 32 + t2 * 16 + r;
                int ci = s * 32 + seg * 8;
                w2[k][t2][s] = *(const bf16x8*)(W2T + ((size_t)(k * CO + co)) * CO + ci);
            }

    // BN1 consts for this thread's staging channels ci = p*8 .. p*8+7
    float scP[8], shP[8];
#pragma unroll
    for (int j = 0; j < 8; j++) {
        int c0 = p * 8 + j;
        float mu  = stats[c0] * (1.0f / NV);
        float var = stats[64 + c0] * (1.0f / NV) - mu * mu;
        float s   = g1[c0] * rsqrtf(var + EPSV);
        scP[j] = s; shP[j] = b1[c0] - mu * s;
    }

    // per-thread chunk constants: chunk c = w*576 + s*64 + lane
    int ri[9], dstoff[9];
#pragma unroll
    for (int s = 0; s < 9; s++) {
        int c = w * 576 + s * 64 + lane;
        int rIdx = c >> 3;
        int i = (rIdx * 57) >> 9;             // floor(rIdx/9), rIdx<512
        ri[s] = rIdx;
        dstoff[s] = rIdx * 128 + ((p ^ (i & 7)) * 16);
    }

    auto loadIdx = [&](int (&ix)[9], int tile) {
        const int* nb = nbr + (size_t)tile * (16 * KK);
#pragma unroll
        for (int s = 0; s < 9; s++) ix[s] = nb[ri[s]];
    };
    auto loadDat = [&](f32x4 (&d)[9], const int (&ix)[9]) {
#pragma unroll
        for (int s = 0; s < 9; s++)
            d[s] = *(const f32x4*)(h1b + (size_t)ix[s] * CO + p * 8);
    };
    auto xform = [&](char* tb, const f32x4 (&d)[9]) {
#pragma unroll
        for (int s = 0; s < 9; s++) {
            union { f32x4 f; bf16x8 b; } u; u.f = d[s];
            bf16x8 o;
#pragma unroll
            for (int j = 0; j < 8; j++)
                o[j] = (__bf16)fmaxf((float)u.b[j] * scP[j] + shP[j], 0.f);
            *(bf16x8*)(tb + dstoff[s]) = o;
        }
    };

    float ps[2][4], pq[2][4];
#pragma unroll
    for (int t2 = 0; t2 < 2; t2++)
#pragma unroll
        for (int rr = 0; rr < 4; rr++) { ps[t2][rr] = 0.f; pq[t2][rr] = 0.f; }
    const f32x4 z = {0.f, 0.f, 0.f, 0.f};
    const int sw = r & 7;
    const int G = gridDim.x;

    int idxN[9]; f32x4 dat[9];
    int it = blockIdx.x;
    loadIdx(idxN, it);
    loadDat(dat, idxN);                                   // data(it)
    { int t1 = it + G;     loadIdx(idxN, t1 < NG ? t1 : NG - 1); }
    xform(smem[0], dat);                                  // waits data(it)
    loadDat(dat, idxN);                                   // data(it+G)
    { int t2 = it + 2 * G; loadIdx(idxN, t2 < NG ? t2 : NG - 1); }
    __syncthreads();
    int cur = 0;

    for (; it < NG; it += G) {
        // ---- compute tile `it` from smem[cur]: pure ds_read + MFMA ----
        const __bf16* base = (const __bf16*)smem[cur];
        f32x4 acc[2] = {z, z};
#pragma unroll
        for (int k = 0; k < KK; k++) {
            const __bf16* rp = base + (size_t)(r * KK + k) * 64;
            bf16x8 a0 = *(const bf16x8*)(rp + ((seg ^ sw) * 8));
            bf16x8 a1 = *(const bf16x8*)(rp + (((4 + seg) ^ sw) * 8));
            acc[0] = mfma16(w2[k][0][0], a0, acc[0]);   // SWAPPED
            acc[0] = mfma16(w2[k][0][1], a1, acc[0]);
            acc[1] = mfma16(w2[k][1][0], a0, acc[1]);
            acc[1] = mfma16(w2[k][1][1], a1, acc[1]);
        }

        const int vb = it * 16;
#pragma unroll
        for (int t2 = 0; t2 < 2; t2++) {
            size_t off = (size_t)(vb + r) * CO + w * 32 + t2 * 16 + seg * 4;
            if constexpr (BF16OUT) {
                bf16x4 o;
#pragma unroll
                for (int rr = 0; rr < 4; rr++) {
                    float val = acc[t2][rr];
                    o[rr] = (__bf16)val;
                    ps[t2][rr] += val; pq[t2][rr] += val * val;
                }
                __builtin_nontemporal_store(o, (bf16x4*)(y2b + off));
            } else {
#pragma unroll
                for (int rr = 0; rr < 4; rr++) {
                    float val = acc[t2][rr];
                    ps[t2][rr] += val; pq[t2][rr] += val * val;
                }
                __builtin_nontemporal_store(acc[t2], (f32x4*)(y2f + off));
            }
        }

        int nx = it + G;
        if (nx < NG) {
            xform(smem[cur ^ 1], dat);                    // stage tile nx (post-BN)
            loadDat(dat, idxN);                           // issue data(it+2G)
            { int t3 = it + 3 * G; loadIdx(idxN, t3 < NG ? t3 : NG - 1); }
            __syncthreads();
            cur ^= 1;
        }
    }

    // stats: channel = w*32 + t2*16 + seg*4 + rr; sum over r
#pragma unroll
    for (int t2 = 0; t2 < 2; t2++)
#pragma unroll
        for (int rr = 0; rr < 4; rr++) {
            ps[t2][rr] = xred16(ps[t2][rr]);
            pq[t2][rr] = xred16(pq[t2][rr]);
        }
    if (r == 0) {
#pragma unroll
        for (int t2 = 0; t2 < 2; t2++)
#pragma unroll
            for (int rr = 0; rr < 4; rr++) {
                int ch = w * 32 + t2 * 16 + seg * 4 + rr;
                atomicAdd(&stats[4 * 64 + ch], ps[t2][rr]);
                atomicAdd(&stats[5 * 64 + ch], pq[t2][rr]);
            }
    }
}

// ---------------- final: out = relu(BN2(y2) + BNd(xb@WdT)) ----------------
// Transposed dense MFMA -> lane (r,seg) owns channels t4*16+seg*4+{0..3} of
// voxel vb+r: y2 reads are 8B bf16 (or 16B f32 in-place fallback), out writes
// are 16B f32x4 nontemporal.
template <bool BF16IN>
__global__ __launch_bounds__(256, 2) void k_final(
    const __bf16* __restrict__ xb, const __bf16* __restrict__ WdT,
    const __bf16* __restrict__ y2b,
    float* __restrict__ out, const float* __restrict__ stats,
    const float* __restrict__ g2, const float* __restrict__ b2,
    const float* __restrict__ gd, const float* __restrict__ bd) {
    __shared__ float s2[CO], shc[CO], sdv[CO];
    int t = threadIdx.x;
    if (t < CO) {
        float mu2  = stats[4 * 64 + t] * (1.0f / NV);
        float var2 = stats[5 * 64 + t] * (1.0f / NV) - mu2 * mu2;
        float s = g2[t] * rsqrtf(var2 + EPSV);
        float mud  = stats[2 * 64 + t] * (1.0f / NV);
        float vard = stats[3 * 64 + t] * (1.0f / NV) - mud * mud;
        float sd = gd[t] * rsqrtf(vard + EPSV);
        s2[t] = s; sdv[t] = sd;
        shc[t] = (b2[t] - mu2 * s) + (bd[t] - mud * sd);
    }
    __syncthreads();

    const int lane = threadIdx.x & 63;
    const int w    = threadIdx.x >> 6;
    const int r    = lane & 15;
    const int seg  = lane >> 4;

    bf16x8 wd[4];
#pragma unroll
    for (int t4 = 0; t4 < 4; t4++)
        wd[t4] = *(const bf16x8*)(WdT + (size_t)(t4 * 16 + r) * CI + seg * 8);

    const int slot = blockIdx.x * 4 + w;
    const int nslots = gridDim.x * 4;
    const f32x4 z = {0.f, 0.f, 0.f, 0.f};

    for (int gid = slot; gid < NG; gid += nslots) {
        const int vb = gid * 16;
        bf16x8 ad = *(const bf16x8*)(xb + (size_t)(vb + r) * CI + seg * 8);
        f32x4 accd[4] = {z, z, z, z};
#pragma unroll
        for (int t4 = 0; t4 < 4; t4++) accd[t4] = mfma16(wd[t4], ad, accd[t4]); // SWAPPED

#pragma unroll
        for (int t4 = 0; t4 < 4; t4++) {
            int cb = t4 * 16 + seg * 4;
            size_t off = (size_t)(vb + r) * CO + cb;
            f32x4 yv;
            if constexpr (BF16IN) {
                bf16x4 yb = *(const bf16x4*)(y2b + off);
#pragma unroll
                for (int rr = 0; rr < 4; rr++) yv[rr] = (float)yb[rr];
            } else {
                yv = *(const f32x4*)(out + off);
            }
            f32x4 s2v  = *(const f32x4*)&s2[cb];
            f32x4 shcv = *(const f32x4*)&shc[cb];
            f32x4 sdvv = *(const f32x4*)&sdv[cb];
            f32x4 o;
#pragma unroll
            for (int rr = 0; rr < 4; rr++)
                o[rr] = fmaxf(s2v[rr] * yv[rr] + shcv[rr] + sdvv[rr] * accd[t4][rr], 0.f);
            __builtin_nontemporal_store(o, (f32x4*)(out + off));
        }
    }
}

extern "C" void kernel_launch(void* const* d_in, const int* in_sizes, int n_in,
                              void* d_out, int out_size, void* d_ws, size_t ws_size,
                              hipStream_t stream) {
    const float* x  = (const float*)d_in[0];
    const float* W1 = (const float*)d_in[1];
    const float* g1 = (const float*)d_in[2];
    const float* b1 = (const float*)d_in[3];
    const float* W2 = (const float*)d_in[4];
    const float* g2 = (const float*)d_in[5];
    const float* b2 = (const float*)d_in[6];
    const float* Wd = (const float*)d_in[7];
    const float* gd = (const float*)d_in[8];
    const float* bd = (const float*)d_in[9];
    const int*  nbr = (const int*)d_in[10];

    char* ws = (char*)d_ws;
    __bf16* xb  = (__bf16*)ws;                              // 64,000,000 B
    __bf16* y1b = (__bf16*)(ws + 64000000);                 // 128,000,000 B
    __bf16* W1T = (__bf16*)(ws + 192000000);                // 36,864 B
    __bf16* W2T = W1T + KK * CO * CI;                       // 73,728 B
    __bf16* WdT = W2T + KK * CO * CO;                       // 4,096 B
    float* stats = (float*)(ws + 192000000 + 2 * (KK*CO*CI + KK*CO*CO + CO*CI));
    // y2 bf16 buffer (if workspace allows): after stats, 256B-aligned
    size_t y2off = ((192000000 + 2 * (KK*CO*CI + KK*CO*CO + CO*CI) + 6*64*4) + 255) & ~(size_t)255;
    __bf16* y2b = (__bf16*)(ws + y2off);
    bool bf16y2 = (ws_size >= y2off + (size_t)NV * CO * 2 + 256);

    hipMemsetAsync(stats, 0, 6 * 64 * sizeof(float), stream);

    int nprep = KK*CO*CI + KK*CO*CO + CO*CI;                // 57344
    k_prep_w<<<(nprep + 255) / 256, 256, 0, stream>>>(W1, W2, Wd, W1T, W2T, WdT);
    k_prep_x<<<(NV * CI / 8) / 256, 256, 0, stream>>>(x, xb);   // 15625 blocks
    k_conv1<<<768, 256, 0, stream>>>(xb, nbr, W1T, WdT, y1b, stats);
    if (bf16y2) {
        k_conv2<true><<<1024, 128, 0, stream>>>(y1b, nbr, W2T, g1, b1,
                                                y2b, nullptr, stats);
        k_final<true><<<1024, 256, 0, stream>>>(xb, WdT, y2b, (float*)d_out, stats,
                                                g2, b2, gd, bd);
    } else {
        k_conv2<false><<<1024, 128, 0, stream>>>(y1b, nbr, W2T, g1, b1,
                                                 nullptr, (float*)d_out, stats);
        k_final<false><<<1024, 256, 0, stream>>>(xb, WdT, nullptr, (float*)d_out, stats,
                                                 g2, b2, gd, bd);
    }
}

// Round 8
// 601.524 us; speedup vs baseline: 1.6008x; 1.6008x over previous
//
#include <hip/hip_runtime.h>
#include <hip/hip_bf16.h>

#define NV 1000000
#define CI 32
#define CO 64
#define KK 9
#define NG (NV / 16)          // 62500 voxel-groups of 16 (exact)
#define EPSV 1e-5f

typedef __bf16 bf16x8 __attribute__((ext_vector_type(8)));
typedef float  f32x4  __attribute__((ext_vector_type(4)));

__device__ __forceinline__ f32x4 mfma16(bf16x8 a, bf16x8 b, f32x4 c) {
    // D[16x16] = A[16x32] * B[32x16] + C
    // A: row=lane&15, k=(lane>>4)*8+j ; B: col=lane&15, k=(lane>>4)*8+j
    // D: col=lane&15, row=(lane>>4)*4+reg   [learn_hip m89 verified]
    return __builtin_amdgcn_mfma_f32_16x16x32_bf16(a, b, c, 0, 0, 0);
}

__device__ __forceinline__ float xredseg(float v) {   // sum over lane{+16,+32}
    v += __shfl_xor(v, 16, 64);
    v += __shfl_xor(v, 32, 64);
    return v;
}

// ---------------- prep: transpose weights to [k][co][ci] bf16 ----------------
__global__ void k_prep_w(const float* __restrict__ W1, const float* __restrict__ W2,
                         const float* __restrict__ Wd,
                         __bf16* __restrict__ W1T, __bf16* __restrict__ W2T,
                         __bf16* __restrict__ WdT) {
    int i = blockIdx.x * blockDim.x + threadIdx.x;
    const int n1 = KK * CO * CI;      // 18432
    const int n2 = KK * CO * CO;      // 36864
    const int nd = CO * CI;           // 2048
    if (i < n1) {
        int k = i / (CO * CI), r = i % (CO * CI), co = r / CI, ci = r % CI;
        W1T[i] = (__bf16)W1[(k * CI + ci) * CO + co];
    } else if (i < n1 + n2) {
        int j = i - n1;
        int k = j / (CO * CO), r = j % (CO * CO), co = r / CO, ci = r % CO;
        W2T[j] = (__bf16)W2[(k * CO + ci) * CO + co];
    } else if (i < n1 + n2 + nd) {
        int j = i - n1 - n2;
        int co = j / CI, ci = j % CI;
        WdT[j] = (__bf16)Wd[ci * CO + co];
    }
}

// ---------------- prep: x fp32 -> bf16 ----------------
__global__ void k_prep_x(const float* __restrict__ x, __bf16* __restrict__ xb) {
    int i = blockIdx.x * blockDim.x + threadIdx.x;   // one thread per 8 elems
    const float4* px = (const float4*)x + 2 * (size_t)i;
    float4 u = px[0], v = px[1];
    bf16x8 o;
    o[0] = (__bf16)u.x; o[1] = (__bf16)u.y; o[2] = (__bf16)u.z; o[3] = (__bf16)u.w;
    o[4] = (__bf16)v.x; o[5] = (__bf16)v.y; o[6] = (__bf16)v.z; o[7] = (__bf16)v.w;
    *((bf16x8*)xb + i) = o;
}

// ---------------- conv1: reg-double-buffered gather-MFMA, W1 in LDS ----------
// ROUND-4 structure (last known good, ~216 µs) + W1-LDS bank-conflict fix:
// the read  r*64B + seg*16B  was an 8-way conflict (9M SQ_LDS_BANK_CONFLICT).
// Fix: seg-slot XOR swizzle  sseg = seg ^ ((r>>1)&3)  -> exactly 2-way (free).
// Swizzle is applied on BOTH sides per rule #21: global SOURCE chunk index at
// staging (global_load_lds LDS dest must stay linear) and the per-lane-constant
// read offset.
__global__ __launch_bounds__(256, 2) void k_conv1(
    const __bf16* __restrict__ xb, const int* __restrict__ nbr,
    const __bf16* __restrict__ W1T, const __bf16* __restrict__ WdT,
    __bf16* __restrict__ y1b, float* __restrict__ stats) {
    __shared__ __align__(16) char w1smem[KK * CO * CI * 2];   // 36864 B

    const int lane = threadIdx.x & 63;
    const int w    = threadIdx.x >> 6;
    const int r    = lane & 15;
    const int seg  = lane >> 4;
    const int sseg = seg ^ ((r >> 1) & 3);   // swizzled seg-slot (per-lane const)

    // stage W1T -> LDS: 2304 16B-chunks, 256 threads x 9, SOURCE pre-swizzled
#pragma unroll
    for (int j = 0; j < 9; j++) {
        int c    = j * 256 + threadIdx.x;              // linear LDS chunk id
        int segc = c & 3;
        int rc   = (c >> 2) & 15;
        int csrc = (c & ~3) | (segc ^ ((rc >> 1) & 3));
        const __bf16* srcp = W1T + (size_t)csrc * 8;
        __builtin_amdgcn_global_load_lds(
            (const __attribute__((address_space(1))) void*)srcp,
            (__attribute__((address_space(3))) void*)(w1smem + j * 4096 + w * 1024),
            16, 0, 0);
    }
    __syncthreads();

    bf16x8 wd[4];
#pragma unroll
    for (int t = 0; t < 4; t++)
        wd[t] = *(const bf16x8*)(WdT + (size_t)(t * 16 + r) * CI + seg * 8);

    float ps1[4] = {0.f,0.f,0.f,0.f}, pq1[4] = {0.f,0.f,0.f,0.f};
    float psd[4] = {0.f,0.f,0.f,0.f}, pqd[4] = {0.f,0.f,0.f,0.f};

    const int slot   = blockIdx.x * 4 + w;
    const int stride = gridDim.x * 4;
    const f32x4 z = {0.f, 0.f, 0.f, 0.f};

    auto loadIdx = [&](int (&idx)[KK], int tile) {
        const int* nb = nbr + (size_t)(tile * 16 + r) * KK;
#pragma unroll
        for (int k = 0; k < KK; k++) idx[k] = nb[k];
    };
    auto gather9 = [&](bf16x8 (&g)[KK], const int (&idx)[KK]) {
#pragma unroll
        for (int k = 0; k < KK; k++)
            g[k] = *(const bf16x8*)(xb + (size_t)idx[k] * CI + seg * 8);
    };
    auto loadAd = [&](int tile) {
        return *(const bf16x8*)(xb + (size_t)(tile * 16 + r) * CI + seg * 8);
    };
    auto compute = [&](int tile, const bf16x8 (&g)[KK], bf16x8 ad) {
        int w1off = 0;
        asm volatile("" : "+v"(w1off));        // defeat cross-iteration hoisting
        const __bf16* wb = (const __bf16*)w1smem + w1off;

        f32x4 acc[4]  = {z, z, z, z};
        f32x4 accd[4] = {z, z, z, z};
#pragma unroll
        for (int t = 0; t < 4; t++) accd[t] = mfma16(ad, wd[t], accd[t]);
#pragma unroll
        for (int k = 0; k < KK; k++) {
#pragma unroll
            for (int t = 0; t < 4; t++) {
                bf16x8 b = *(const bf16x8*)(wb + k * 2048 + t * 512 + r * 32 + sseg * 8);
                acc[t] = mfma16(g[k], b, acc[t]);
            }
        }

        const int vb = tile * 16;
#pragma unroll
        for (int t = 0; t < 4; t++) {
#pragma unroll
            for (int rr = 0; rr < 4; rr++) {
                float val = acc[t][rr];
                int row = vb + seg * 4 + rr;
                __builtin_nontemporal_store((__bf16)val, &y1b[(size_t)row * CO + t * 16 + r]);
                ps1[t] += val; pq1[t] += val * val;
                float dv = accd[t][rr];
                psd[t] += dv; pqd[t] += dv * dv;
            }
        }
    };

    int idx0[KK], idx1[KK];
    bf16x8 g0[KK], g1[KK];
    bf16x8 ad0, ad1;

    int it = slot;                    // slot < 3072 <= NG always
    loadIdx(idx0, it);
    gather9(g0, idx0); ad0 = loadAd(it);
    int itn = it + stride;
    bool have = (itn < NG);
    if (have) loadIdx(idx1, itn);

    while (true) {
        if (have) {
            gather9(g1, idx1); ad1 = loadAd(itn);
            int it2 = itn + stride;
            if (it2 < NG) loadIdx(idx0, it2);
        }
        compute(it, g0, ad0);
        if (!have) break;
        it = itn; itn = it + stride; have = (itn < NG);

        if (have) {
            gather9(g0, idx0); ad0 = loadAd(itn);
            int it2 = itn + stride;
            if (it2 < NG) loadIdx(idx1, it2);
        }
        compute(it, g1, ad1);
        if (!have) break;
        it = itn; itn = it + stride; have = (itn < NG);
    }

#pragma unroll
    for (int t = 0; t < 4; t++) {
        ps1[t] = xredseg(ps1[t]); pq1[t] = xredseg(pq1[t]);
        psd[t] = xredseg(psd[t]); pqd[t] = xredseg(pqd[t]);
    }
    if (lane < 16) {
#pragma unroll
        for (int t = 0; t < 4; t++) {
            atomicAdd(&stats[0 * 64 + t * 16 + lane], ps1[t]);
            atomicAdd(&stats[1 * 64 + t * 16 + lane], pq1[t]);
            atomicAdd(&stats[2 * 64 + t * 16 + lane], psd[t]);
            atomicAdd(&stats[3 * 64 + t * 16 + lane], pqd[t]);
        }
    }
}

// ---------------- conv2: reg-staged gather, BN1+ReLU once at staging ----------
// ROUND-5 version verbatim (measured ~236 µs): global->reg->BN+ReLU->swizzled
// ds_write staging; compute phase is pure ds_read+MFMA; f32 y2 out (d_out), nt.
#define TILE_B (16 * KK * 128)     // 18432 B per buffer

__global__ __launch_bounds__(128, 2) void k_conv2(
    const __bf16* __restrict__ h1b, const int* __restrict__ nbr,
    const __bf16* __restrict__ W2T, const float* __restrict__ g1,
    const float* __restrict__ b1,
    float* __restrict__ y2, float* __restrict__ stats) {
    __shared__ __align__(16) char smem[2][TILE_B];   // 36864 B -> 4 blocks/CU

    const int lane = threadIdx.x & 63;
    const int w    = threadIdx.x >> 6;      // 0..1 = co-half
    const int r    = lane & 15;
    const int seg  = lane >> 4;
    const int p    = lane & 7;              // staging channel-chunk (static)

    bf16x8 w2[KK][2][2];                    // [k][t2][s]
#pragma unroll
    for (int k = 0; k < KK; k++)
#pragma unroll
        for (int t2 = 0; t2 < 2; t2++)
#pragma unroll
            for (int s = 0; s < 2; s++) {
                int co = w * 32 + t2 * 16 + r;
                int ci = s * 32 + seg * 8;
                w2[k][t2][s] = *(const bf16x8*)(W2T + ((size_t)(k * CO + co)) * CO + ci);
            }

    // BN1 consts for this thread's staging channels ci = p*8 .. p*8+7
    float scP[8], shP[8];
#pragma unroll
    for (int j = 0; j < 8; j++) {
        int c0 = p * 8 + j;
        float mu  = stats[c0] * (1.0f / NV);
        float var = stats[64 + c0] * (1.0f / NV) - mu * mu;
        float s   = g1[c0] * rsqrtf(var + EPSV);
        scP[j] = s; shP[j] = b1[c0] - mu * s;
    }

    // per-thread chunk constants: chunk c = w*576 + s*64 + lane
    int ri[9], dstoff[9];
#pragma unroll
    for (int s = 0; s < 9; s++) {
        int c = w * 576 + s * 64 + lane;
        int rIdx = c >> 3;
        int i = (rIdx * 57) >> 9;             // floor(rIdx/9), rIdx<512
        ri[s] = rIdx;
        dstoff[s] = rIdx * 128 + ((p ^ (i & 7)) * 16);
    }

    auto loadIdx = [&](int (&ix)[9], int tile) {
        const int* nb = nbr + (size_t)tile * (16 * KK);
#pragma unroll
        for (int s = 0; s < 9; s++) ix[s] = nb[ri[s]];
    };
    auto loadDat = [&](f32x4 (&d)[9], const int (&ix)[9]) {
#pragma unroll
        for (int s = 0; s < 9; s++)
            d[s] = *(const f32x4*)(h1b + (size_t)ix[s] * CO + p * 8);
    };
    auto xform = [&](char* tb, const f32x4 (&d)[9]) {
#pragma unroll
        for (int s = 0; s < 9; s++) {
            union { f32x4 f; bf16x8 b; } u; u.f = d[s];
            bf16x8 o;
#pragma unroll
            for (int j = 0; j < 8; j++)
                o[j] = (__bf16)fmaxf((float)u.b[j] * scP[j] + shP[j], 0.f);
            *(bf16x8*)(tb + dstoff[s]) = o;
        }
    };

    float ps[2] = {0.f, 0.f}, pq[2] = {0.f, 0.f};
    const f32x4 z = {0.f, 0.f, 0.f, 0.f};
    const int sw = r & 7;
    const int G = gridDim.x;

    int idxN[9]; f32x4 dat[9];
    int it = blockIdx.x;
    loadIdx(idxN, it);
    loadDat(dat, idxN);                                   // data(it)
    { int t1 = it + G;     loadIdx(idxN, t1 < NG ? t1 : NG - 1); }
    xform(smem[0], dat);                                  // waits data(it)
    loadDat(dat, idxN);                                   // data(it+G)
    { int t2 = it + 2 * G; loadIdx(idxN, t2 < NG ? t2 : NG - 1); }
    __syncthreads();
    int cur = 0;

    for (; it < NG; it += G) {
        // ---- compute tile `it` from smem[cur]: pure ds_read + MFMA ----
        const __bf16* base = (const __bf16*)smem[cur];
        f32x4 acc[2] = {z, z};
#pragma unroll
        for (int k = 0; k < KK; k++) {
            const __bf16* rp = base + (size_t)(r * KK + k) * 64;
            bf16x8 a0 = *(const bf16x8*)(rp + ((seg ^ sw) * 8));
            bf16x8 a1 = *(const bf16x8*)(rp + (((4 + seg) ^ sw) * 8));
            acc[0] = mfma16(a0, w2[k][0][0], acc[0]);
            acc[0] = mfma16(a1, w2[k][0][1], acc[0]);
            acc[1] = mfma16(a0, w2[k][1][0], acc[1]);
            acc[1] = mfma16(a1, w2[k][1][1], acc[1]);
        }

        const int vb = it * 16;
#pragma unroll
        for (int t2 = 0; t2 < 2; t2++) {
#pragma unroll
            for (int rr = 0; rr < 4; rr++) {
                float val = acc[t2][rr];
                int row = vb + seg * 4 + rr;
                int c = w * 32 + t2 * 16 + r;
                __builtin_nontemporal_store(val, &y2[(size_t)row * CO + c]);
                ps[t2] += val; pq[t2] += val * val;
            }
        }

        int nx = it + G;
        if (nx < NG) {
            xform(smem[cur ^ 1], dat);                    // stage tile nx (post-BN)
            loadDat(dat, idxN);                           // issue data(it+2G)
            { int t3 = it + 3 * G; loadIdx(idxN, t3 < NG ? t3 : NG - 1); }
            __syncthreads();
            cur ^= 1;
        }
    }

#pragma unroll
    for (int t2 = 0; t2 < 2; t2++) { ps[t2] = xredseg(ps[t2]); pq[t2] = xredseg(pq[t2]); }
    if (lane < 16) {
#pragma unroll
        for (int t2 = 0; t2 < 2; t2++) {
            atomicAdd(&stats[4 * 64 + w * 32 + t2 * 16 + lane], ps[t2]);
            atomicAdd(&stats[5 * 64 + w * 32 + t2 * 16 + lane], pq[t2]);
        }
    }
}

// ---------------- final: out = relu(BN2(y2) + BNd(xb@WdT)), in place ----------
// ROUND-4/5 version verbatim (~91 µs).
__global__ __launch_bounds__(256, 2) void k_final(
    const __bf16* __restrict__ xb, const __bf16* __restrict__ WdT,
    float* __restrict__ out, const float* __restrict__ stats,
    const float* __restrict__ g2, const float* __restrict__ b2,
    const float* __restrict__ gd, const float* __restrict__ bd) {
    __shared__ float s2[CO], sh2[CO], sdv[CO], shd[CO];
    int t = threadIdx.x;
    if (t < CO) {
        float mu2  = stats[4 * 64 + t] * (1.0f / NV);
        float var2 = stats[5 * 64 + t] * (1.0f / NV) - mu2 * mu2;
        float s = g2[t] * rsqrtf(var2 + EPSV);
        s2[t] = s; sh2[t] = b2[t] - mu2 * s;
        float mud  = stats[2 * 64 + t] * (1.0f / NV);
        float vard = stats[3 * 64 + t] * (1.0f / NV) - mud * mud;
        float sd = gd[t] * rsqrtf(vard + EPSV);
        sdv[t] = sd; shd[t] = bd[t] - mud * sd;
    }
    __syncthreads();

    const int lane = threadIdx.x & 63;
    const int w    = threadIdx.x >> 6;
    const int r    = lane & 15;
    const int seg  = lane >> 4;

    bf16x8 wd[4];
#pragma unroll
    for (int t4 = 0; t4 < 4; t4++)
        wd[t4] = *(const bf16x8*)(WdT + (size_t)(t4 * 16 + r) * CI + seg * 8);

    const int slot = blockIdx.x * 4 + w;
    const int nslots = gridDim.x * 4;
    const f32x4 z = {0.f, 0.f, 0.f, 0.f};

    for (int gid = slot; gid < NG; gid += nslots) {
        const int vb = gid * 16;
        const int v  = vb + r;
        bf16x8 ad = *(const bf16x8*)(xb + (size_t)v * CI + seg * 8);
        f32x4 accd[4] = {z, z, z, z};
#pragma unroll
        for (int t4 = 0; t4 < 4; t4++) accd[t4] = mfma16(ad, wd[t4], accd[t4]);
#pragma unroll
        for (int t4 = 0; t4 < 4; t4++) {
#pragma unroll
            for (int rr = 0; rr < 4; rr++) {
                int row = vb + seg * 4 + rr;
                int c = t4 * 16 + r;
                size_t o = (size_t)row * CO + c;
                float y2v = out[o];
                float res = s2[c] * y2v + sh2[c] + sdv[c] * accd[t4][rr] + shd[c];
                out[o] = fmaxf(res, 0.f);
            }
        }
    }
}

extern "C" void kernel_launch(void* const* d_in, const int* in_sizes, int n_in,
                              void* d_out, int out_size, void* d_ws, size_t ws_size,
                              hipStream_t stream) {
    const float* x  = (const float*)d_in[0];
    const float* W1 = (const float*)d_in[1];
    const float* g1 = (const float*)d_in[2];
    const float* b1 = (const float*)d_in[3];
    const float* W2 = (const float*)d_in[4];
    const float* g2 = (const float*)d_in[5];
    const float* b2 = (const float*)d_in[6];
    const float* Wd = (const float*)d_in[7];
    const float* gd = (const float*)d_in[8];
    const float* bd = (const float*)d_in[9];
    const int*  nbr = (const int*)d_in[10];

    char* ws = (char*)d_ws;
    __bf16* xb  = (__bf16*)ws;                              // 64,000,000 B
    __bf16* y1b = (__bf16*)(ws + 64000000);                 // 128,000,000 B
    __bf16* W1T = (__bf16*)(ws + 192000000);                // 36,864 B
    __bf16* W2T = W1T + KK * CO * CI;                       // 73,728 B
    __bf16* WdT = W2T + KK * CO * CO;                       // 4,096 B
    float* stats = (float*)(ws + 192000000 + 2 * (KK*CO*CI + KK*CO*CO + CO*CI));

    hipMemsetAsync(stats, 0, 6 * 64 * sizeof(float), stream);

    int nprep = KK*CO*CI + KK*CO*CO + CO*CI;                // 57344
    k_prep_w<<<(nprep + 255) / 256, 256, 0, stream>>>(W1, W2, Wd, W1T, W2T, WdT);
    k_prep_x<<<(NV * CI / 8) / 256, 256, 0, stream>>>(x, xb);   // 15625 blocks
    k_conv1<<<768, 256, 0, stream>>>(xb, nbr, W1T, WdT, y1b, stats);
    k_conv2<<<1024, 128, 0, stream>>>(y1b, nbr, W2T, g1, b1, (float*)d_out, stats);
    k_final<<<1024, 256, 0, stream>>>(xb, WdT, (float*)d_out, stats, g2, b2, gd, bd);
}

// Round 9
// 591.298 us; speedup vs baseline: 1.6285x; 1.0173x over previous
//
#include <hip/hip_runtime.h>
#include <hip/hip_bf16.h>

#define NV 1000000
#define CI 32
#define CO 64
#define KK 9
#define NG (NV / 16)          // 62500 voxel-groups of 16 (exact)
#define EPSV 1e-5f

typedef __bf16 bf16x8 __attribute__((ext_vector_type(8)));
typedef __bf16 bf16x4 __attribute__((ext_vector_type(4)));
typedef float  f32x4  __attribute__((ext_vector_type(4)));

__device__ __forceinline__ f32x4 mfma16(bf16x8 a, bf16x8 b, f32x4 c) {
    // D[16x16] = A[16x32] * B[32x16] + C
    // A: row=lane&15, k=(lane>>4)*8+j ; B: col=lane&15, k=(lane>>4)*8+j
    // D: col=lane&15, row=(lane>>4)*4+reg   [learn_hip m89 verified]
    return __builtin_amdgcn_mfma_f32_16x16x32_bf16(a, b, c, 0, 0, 0);
}

__device__ __forceinline__ float xredseg(float v) {   // sum over lane{+16,+32}
    v += __shfl_xor(v, 16, 64);
    v += __shfl_xor(v, 32, 64);
    return v;
}

// ---------------- prep: transpose weights to [k][co][ci] bf16 ----------------
__global__ void k_prep_w(const float* __restrict__ W1, const float* __restrict__ W2,
                         const float* __restrict__ Wd,
                         __bf16* __restrict__ W1T, __bf16* __restrict__ W2T,
                         __bf16* __restrict__ WdT) {
    int i = blockIdx.x * blockDim.x + threadIdx.x;
    const int n1 = KK * CO * CI;      // 18432
    const int n2 = KK * CO * CO;      // 36864
    const int nd = CO * CI;           // 2048
    if (i < n1) {
        int k = i / (CO * CI), r = i % (CO * CI), co = r / CI, ci = r % CI;
        W1T[i] = (__bf16)W1[(k * CI + ci) * CO + co];
    } else if (i < n1 + n2) {
        int j = i - n1;
        int k = j / (CO * CO), r = j % (CO * CO), co = r / CO, ci = r % CO;
        W2T[j] = (__bf16)W2[(k * CO + ci) * CO + co];
    } else if (i < n1 + n2 + nd) {
        int j = i - n1 - n2;
        int co = j / CI, ci = j % CI;
        WdT[j] = (__bf16)Wd[ci * CO + co];
    }
}

// ---------------- prep: x fp32 -> bf16 ----------------
__global__ void k_prep_x(const float* __restrict__ x, __bf16* __restrict__ xb) {
    int i = blockIdx.x * blockDim.x + threadIdx.x;   // one thread per 8 elems
    const float4* px = (const float4*)x + 2 * (size_t)i;
    float4 u = px[0], v = px[1];
    bf16x8 o;
    o[0] = (__bf16)u.x; o[1] = (__bf16)u.y; o[2] = (__bf16)u.z; o[3] = (__bf16)u.w;
    o[4] = (__bf16)v.x; o[5] = (__bf16)v.y; o[6] = (__bf16)v.z; o[7] = (__bf16)v.w;
    *((bf16x8*)xb + i) = o;
}

// ---------------- conv1: reg-double-buffered gather-MFMA, W1 in LDS ----------
// Round-8 structure + COALESCED STORES: the 16x 2-B nt scatter stores per tile
// (WRITE_SIZE 240 MB for a 128 MB buffer = partial-sector inflation) are
// replaced by per-wave LDS staging (XOR-swizzled, key=row&7 both sides) and
// 2x dense 16-B nt stores per lane. ds ops ride lgkmcnt -> vmcnt gather
// pipeline untouched.
__global__ __launch_bounds__(256, 2) void k_conv1(
    const __bf16* __restrict__ xb, const int* __restrict__ nbr,
    const __bf16* __restrict__ W1T, const __bf16* __restrict__ WdT,
    __bf16* __restrict__ y1b, float* __restrict__ stats) {
    __shared__ __align__(16) char w1smem[KK * CO * CI * 2];   // 36864 B
    __shared__ __align__(16) char ystage[4][2048];            // per-wave C staging

    const int lane = threadIdx.x & 63;
    const int w    = threadIdx.x >> 6;
    const int r    = lane & 15;
    const int seg  = lane >> 4;
    const int sseg = seg ^ ((r >> 1) & 3);   // W1-LDS read swizzle (round 8)

    // stage W1T -> LDS: 2304 16B-chunks, 256 threads x 9, SOURCE pre-swizzled
#pragma unroll
    for (int j = 0; j < 9; j++) {
        int c    = j * 256 + threadIdx.x;              // linear LDS chunk id
        int segc = c & 3;
        int rc   = (c >> 2) & 15;
        int csrc = (c & ~3) | (segc ^ ((rc >> 1) & 3));
        const __bf16* srcp = W1T + (size_t)csrc * 8;
        __builtin_amdgcn_global_load_lds(
            (const __attribute__((address_space(1))) void*)srcp,
            (__attribute__((address_space(3))) void*)(w1smem + j * 4096 + w * 1024),
            16, 0, 0);
    }
    __syncthreads();

    bf16x8 wd[4];
#pragma unroll
    for (int t = 0; t < 4; t++)
        wd[t] = *(const bf16x8*)(WdT + (size_t)(t * 16 + r) * CI + seg * 8);

    float ps1[4] = {0.f,0.f,0.f,0.f}, pq1[4] = {0.f,0.f,0.f,0.f};
    float psd[4] = {0.f,0.f,0.f,0.f}, pqd[4] = {0.f,0.f,0.f,0.f};

    const int slot   = blockIdx.x * 4 + w;
    const int stride = gridDim.x * 4;
    const f32x4 z = {0.f, 0.f, 0.f, 0.f};

    auto loadIdx = [&](int (&idx)[KK], int tile) {
        const int* nb = nbr + (size_t)(tile * 16 + r) * KK;
#pragma unroll
        for (int k = 0; k < KK; k++) idx[k] = nb[k];
    };
    auto gather9 = [&](bf16x8 (&g)[KK], const int (&idx)[KK]) {
#pragma unroll
        for (int k = 0; k < KK; k++)
            g[k] = *(const bf16x8*)(xb + (size_t)idx[k] * CI + seg * 8);
    };
    auto loadAd = [&](int tile) {
        return *(const bf16x8*)(xb + (size_t)(tile * 16 + r) * CI + seg * 8);
    };
    auto compute = [&](int tile, const bf16x8 (&g)[KK], bf16x8 ad) {
        int w1off = 0;
        asm volatile("" : "+v"(w1off));        // defeat cross-iteration hoisting
        const __bf16* wb = (const __bf16*)w1smem + w1off;

        f32x4 acc[4]  = {z, z, z, z};
        f32x4 accd[4] = {z, z, z, z};
#pragma unroll
        for (int t = 0; t < 4; t++) accd[t] = mfma16(ad, wd[t], accd[t]);
#pragma unroll
        for (int k = 0; k < KK; k++) {
#pragma unroll
            for (int t = 0; t < 4; t++) {
                bf16x8 b = *(const bf16x8*)(wb + k * 2048 + t * 512 + r * 32 + sseg * 8);
                acc[t] = mfma16(g[k], b, acc[t]);
            }
        }

        const int vb = tile * 16;
        // ---- stage C to per-wave LDS (swizzled, key = row&7) ----
        char* yst = ystage[w];
#pragma unroll
        for (int t = 0; t < 4; t++) {
#pragma unroll
            for (int rr = 0; rr < 4; rr++) {
                float val = acc[t][rr];             // y1[vb+row][t*16+r], row=seg*4+rr
                ps1[t] += val; pq1[t] += val * val;
                float dv = accd[t][rr];
                psd[t] += dv; pqd[t] += dv * dv;
                int row = seg * 4 + rr;
                int byte = row * 128 + ((t * 32 + 2 * r) ^ ((row & 7) << 4));
                *(__bf16*)(yst + byte) = (__bf16)val;
            }
        }
        // ---- readback + dense 16-B nt stores: lane covers chunks 2l, 2l+1 ----
#pragma unroll
        for (int q = 0; q < 2; q++) {
            int c    = lane * 2 + q;                // 0..127 (16B chunks)
            int row  = c >> 3;
            int part = c & 7;
            bf16x8 v = *(const bf16x8*)(yst + row * 128 + ((part ^ (row & 7)) << 4));
            __builtin_nontemporal_store(
                v, (bf16x8*)(y1b + (size_t)vb * CO + (size_t)c * 8));
        }
    };

    int idx0[KK], idx1[KK];
    bf16x8 g0[KK], g1[KK];
    bf16x8 ad0, ad1;

    int it = slot;                    // slot < 3072 <= NG always
    loadIdx(idx0, it);
    gather9(g0, idx0); ad0 = loadAd(it);
    int itn = it + stride;
    bool have = (itn < NG);
    if (have) loadIdx(idx1, itn);

    while (true) {
        if (have) {
            gather9(g1, idx1); ad1 = loadAd(itn);
            int it2 = itn + stride;
            if (it2 < NG) loadIdx(idx0, it2);
        }
        compute(it, g0, ad0);
        if (!have) break;
        it = itn; itn = it + stride; have = (itn < NG);

        if (have) {
            gather9(g0, idx0); ad0 = loadAd(itn);
            int it2 = itn + stride;
            if (it2 < NG) loadIdx(idx1, it2);
        }
        compute(it, g1, ad1);
        if (!have) break;
        it = itn; itn = it + stride; have = (itn < NG);
    }

#pragma unroll
    for (int t = 0; t < 4; t++) {
        ps1[t] = xredseg(ps1[t]); pq1[t] = xredseg(pq1[t]);
        psd[t] = xredseg(psd[t]); pqd[t] = xredseg(pqd[t]);
    }
    if (lane < 16) {
#pragma unroll
        for (int t = 0; t < 4; t++) {
            atomicAdd(&stats[0 * 64 + t * 16 + lane], ps1[t]);
            atomicAdd(&stats[1 * 64 + t * 16 + lane], pq1[t]);
            atomicAdd(&stats[2 * 64 + t * 16 + lane], psd[t]);
            atomicAdd(&stats[3 * 64 + t * 16 + lane], pqd[t]);
        }
    }
}

// ---------------- conv2: reg-staged gather, BN1+ReLU once at staging ----------
// Round-8 structure; output path changed: y2 stored BF16 (if workspace allows)
// via per-wave LDS staging (key = row>>2) -> dense 16-B nt stores. Fallback:
// old f32 nt scatter into d_out.
#define TILE_B (16 * KK * 128)     // 18432 B per buffer

template <bool BF16OUT>
__global__ __launch_bounds__(128, 2) void k_conv2(
    const __bf16* __restrict__ h1b, const int* __restrict__ nbr,
    const __bf16* __restrict__ W2T, const float* __restrict__ g1,
    const float* __restrict__ b1,
    __bf16* __restrict__ y2b, float* __restrict__ y2f,
    float* __restrict__ stats) {
    __shared__ __align__(16) char smem[2][TILE_B];   // 36864 B
    __shared__ __align__(16) char ystage2[2][1024];  // per-wave C staging (bf16 path)

    const int lane = threadIdx.x & 63;
    const int w    = threadIdx.x >> 6;      // 0..1 = co-half
    const int r    = lane & 15;
    const int seg  = lane >> 4;
    const int p    = lane & 7;              // staging channel-chunk (static)

    bf16x8 w2[KK][2][2];                    // [k][t2][s]
#pragma unroll
    for (int k = 0; k < KK; k++)
#pragma unroll
        for (int t2 = 0; t2 < 2; t2++)
#pragma unroll
            for (int s = 0; s < 2; s++) {
                int co = w * 32 + t2 * 16 + r;
                int ci = s * 32 + seg * 8;
                w2[k][t2][s] = *(const bf16x8*)(W2T + ((size_t)(k * CO + co)) * CO + ci);
            }

    // BN1 consts for this thread's staging channels ci = p*8 .. p*8+7
    float scP[8], shP[8];
#pragma unroll
    for (int j = 0; j < 8; j++) {
        int c0 = p * 8 + j;
        float mu  = stats[c0] * (1.0f / NV);
        float var = stats[64 + c0] * (1.0f / NV) - mu * mu;
        float s   = g1[c0] * rsqrtf(var + EPSV);
        scP[j] = s; shP[j] = b1[c0] - mu * s;
    }

    // per-thread chunk constants: chunk c = w*576 + s*64 + lane
    int ri[9], dstoff[9];
#pragma unroll
    for (int s = 0; s < 9; s++) {
        int c = w * 576 + s * 64 + lane;
        int rIdx = c >> 3;
        int i = (rIdx * 57) >> 9;             // floor(rIdx/9), rIdx<512
        ri[s] = rIdx;
        dstoff[s] = rIdx * 128 + ((p ^ (i & 7)) * 16);
    }

    auto loadIdx = [&](int (&ix)[9], int tile) {
        const int* nb = nbr + (size_t)tile * (16 * KK);
#pragma unroll
        for (int s = 0; s < 9; s++) ix[s] = nb[ri[s]];
    };
    auto loadDat = [&](f32x4 (&d)[9], const int (&ix)[9]) {
#pragma unroll
        for (int s = 0; s < 9; s++)
            d[s] = *(const f32x4*)(h1b + (size_t)ix[s] * CO + p * 8);
    };
    auto xform = [&](char* tb, const f32x4 (&d)[9]) {
#pragma unroll
        for (int s = 0; s < 9; s++) {
            union { f32x4 f; bf16x8 b; } u; u.f = d[s];
            bf16x8 o;
#pragma unroll
            for (int j = 0; j < 8; j++)
                o[j] = (__bf16)fmaxf((float)u.b[j] * scP[j] + shP[j], 0.f);
            *(bf16x8*)(tb + dstoff[s]) = o;
        }
    };

    float ps[2] = {0.f, 0.f}, pq[2] = {0.f, 0.f};
    const f32x4 z = {0.f, 0.f, 0.f, 0.f};
    const int sw = r & 7;
    const int G = gridDim.x;

    int idxN[9]; f32x4 dat[9];
    int it = blockIdx.x;
    loadIdx(idxN, it);
    loadDat(dat, idxN);                                   // data(it)
    { int t1 = it + G;     loadIdx(idxN, t1 < NG ? t1 : NG - 1); }
    xform(smem[0], dat);                                  // waits data(it)
    loadDat(dat, idxN);                                   // data(it+G)
    { int t2 = it + 2 * G; loadIdx(idxN, t2 < NG ? t2 : NG - 1); }
    __syncthreads();
    int cur = 0;

    for (; it < NG; it += G) {
        // ---- compute tile `it` from smem[cur]: pure ds_read + MFMA ----
        const __bf16* base = (const __bf16*)smem[cur];
        f32x4 acc[2] = {z, z};
#pragma unroll
        for (int k = 0; k < KK; k++) {
            const __bf16* rp = base + (size_t)(r * KK + k) * 64;
            bf16x8 a0 = *(const bf16x8*)(rp + ((seg ^ sw) * 8));
            bf16x8 a1 = *(const bf16x8*)(rp + (((4 + seg) ^ sw) * 8));
            acc[0] = mfma16(a0, w2[k][0][0], acc[0]);
            acc[0] = mfma16(a1, w2[k][0][1], acc[0]);
            acc[1] = mfma16(a0, w2[k][1][0], acc[1]);
            acc[1] = mfma16(a1, w2[k][1][1], acc[1]);
        }

        const int vb = it * 16;
        if constexpr (BF16OUT) {
            // stage to per-wave LDS (key = row>>2), then dense 16-B nt stores
            char* yst = ystage2[w];
#pragma unroll
            for (int t2 = 0; t2 < 2; t2++) {
#pragma unroll
                for (int rr = 0; rr < 4; rr++) {
                    float val = acc[t2][rr];        // y2[vb+row][w*32+t2*16+r]
                    ps[t2] += val; pq[t2] += val * val;
                    int row = seg * 4 + rr;
                    int byte = row * 64 + ((t2 * 32 + 2 * r) ^ ((row >> 2) << 4));
                    *(__bf16*)(yst + byte) = (__bf16)val;
                }
            }
            {
                int row  = lane >> 2;               // chunk c = lane, 16B each
                int part = lane & 3;
                bf16x8 v = *(const bf16x8*)(yst + row * 64 + ((part ^ (row >> 2)) << 4));
                __builtin_nontemporal_store(
                    v, (bf16x8*)(y2b + (size_t)(vb + row) * CO + w * 32 + part * 8));
            }
        } else {
#pragma unroll
            for (int t2 = 0; t2 < 2; t2++) {
#pragma unroll
                for (int rr = 0; rr < 4; rr++) {
                    float val = acc[t2][rr];
                    int row = vb + seg * 4 + rr;
                    int c = w * 32 + t2 * 16 + r;
                    __builtin_nontemporal_store(val, &y2f[(size_t)row * CO + c]);
                    ps[t2] += val; pq[t2] += val * val;
                }
            }
        }

        int nx = it + G;
        if (nx < NG) {
            xform(smem[cur ^ 1], dat);                    // stage tile nx (post-BN)
            loadDat(dat, idxN);                           // issue data(it+2G)
            { int t3 = it + 3 * G; loadIdx(idxN, t3 < NG ? t3 : NG - 1); }
            __syncthreads();
            cur ^= 1;
        }
    }

#pragma unroll
    for (int t2 = 0; t2 < 2; t2++) { ps[t2] = xredseg(ps[t2]); pq[t2] = xredseg(pq[t2]); }
    if (lane < 16) {
#pragma unroll
        for (int t2 = 0; t2 < 2; t2++) {
            atomicAdd(&stats[4 * 64 + w * 32 + t2 * 16 + lane], ps[t2]);
            atomicAdd(&stats[5 * 64 + w * 32 + t2 * 16 + lane], pq[t2]);
        }
    }
}

// ---------------- final: out = relu(BN2(y2) + BNd(xb@WdT)) ----------------
// BF16IN: y2 read as bf16 (halves final's y2 traffic). Fallback: f32 in place.
template <bool BF16IN>
__global__ __launch_bounds__(256, 2) void k_final(
    const __bf16* __restrict__ xb, const __bf16* __restrict__ WdT,
    const __bf16* __restrict__ y2b,
    float* __restrict__ out, const float* __restrict__ stats,
    const float* __restrict__ g2, const float* __restrict__ b2,
    const float* __restrict__ gd, const float* __restrict__ bd) {
    __shared__ float s2[CO], sh2[CO], sdv[CO], shd[CO];
    int t = threadIdx.x;
    if (t < CO) {
        float mu2  = stats[4 * 64 + t] * (1.0f / NV);
        float var2 = stats[5 * 64 + t] * (1.0f / NV) - mu2 * mu2;
        float s = g2[t] * rsqrtf(var2 + EPSV);
        s2[t] = s; sh2[t] = b2[t] - mu2 * s;
        float mud  = stats[2 * 64 + t] * (1.0f / NV);
        float vard = stats[3 * 64 + t] * (1.0f / NV) - mud * mud;
        float sd = gd[t] * rsqrtf(vard + EPSV);
        sdv[t] = sd; shd[t] = bd[t] - mud * sd;
    }
    __syncthreads();

    const int lane = threadIdx.x & 63;
    const int w    = threadIdx.x >> 6;
    const int r    = lane & 15;
    const int seg  = lane >> 4;

    bf16x8 wd[4];
#pragma unroll
    for (int t4 = 0; t4 < 4; t4++)
        wd[t4] = *(const bf16x8*)(WdT + (size_t)(t4 * 16 + r) * CI + seg * 8);

    const int slot = blockIdx.x * 4 + w;
    const int nslots = gridDim.x * 4;
    const f32x4 z = {0.f, 0.f, 0.f, 0.f};

    for (int gid = slot; gid < NG; gid += nslots) {
        const int vb = gid * 16;
        const int v  = vb + r;
        bf16x8 ad = *(const bf16x8*)(xb + (size_t)v * CI + seg * 8);
        f32x4 accd[4] = {z, z, z, z};
#pragma unroll
        for (int t4 = 0; t4 < 4; t4++) accd[t4] = mfma16(ad, wd[t4], accd[t4]);
#pragma unroll
        for (int t4 = 0; t4 < 4; t4++) {
#pragma unroll
            for (int rr = 0; rr < 4; rr++) {
                int row = vb + seg * 4 + rr;
                int c = t4 * 16 + r;
                size_t o = (size_t)row * CO + c;
                float y2v;
                if constexpr (BF16IN) y2v = (float)y2b[o];
                else                  y2v = out[o];
                float res = s2[c] * y2v + sh2[c] + sdv[c] * accd[t4][rr] + shd[c];
                __builtin_nontemporal_store(fmaxf(res, 0.f), &out[o]);
            }
        }
    }
}

extern "C" void kernel_launch(void* const* d_in, const int* in_sizes, int n_in,
                              void* d_out, int out_size, void* d_ws, size_t ws_size,
                              hipStream_t stream) {
    const float* x  = (const float*)d_in[0];
    const float* W1 = (const float*)d_in[1];
    const float* g1 = (const float*)d_in[2];
    const float* b1 = (const float*)d_in[3];
    const float* W2 = (const float*)d_in[4];
    const float* g2 = (const float*)d_in[5];
    const float* b2 = (const float*)d_in[6];
    const float* Wd = (const float*)d_in[7];
    const float* gd = (const float*)d_in[8];
    const float* bd = (const float*)d_in[9];
    const int*  nbr = (const int*)d_in[10];

    char* ws = (char*)d_ws;
    __bf16* xb  = (__bf16*)ws;                              // 64,000,000 B
    __bf16* y1b = (__bf16*)(ws + 64000000);                 // 128,000,000 B
    __bf16* W1T = (__bf16*)(ws + 192000000);                // 36,864 B
    __bf16* W2T = W1T + KK * CO * CI;                       // 73,728 B
    __bf16* WdT = W2T + KK * CO * CO;                       // 4,096 B
    float* stats = (float*)(ws + 192000000 + 2 * (KK*CO*CI + KK*CO*CO + CO*CI));
    // y2 bf16 buffer (if workspace allows): after stats, 256B-aligned
    size_t y2off = ((192000000 + 2 * (KK*CO*CI + KK*CO*CO + CO*CI) + 6*64*4) + 255) & ~(size_t)255;
    __bf16* y2b = (__bf16*)(ws + y2off);
    bool bf16y2 = (ws_size >= y2off + (size_t)NV * CO * 2 + 256);

    hipMemsetAsync(stats, 0, 6 * 64 * sizeof(float), stream);

    int nprep = KK*CO*CI + KK*CO*CO + CO*CI;                // 57344
    k_prep_w<<<(nprep + 255) / 256, 256, 0, stream>>>(W1, W2, Wd, W1T, W2T, WdT);
    k_prep_x<<<(NV * CI / 8) / 256, 256, 0, stream>>>(x, xb);   // 15625 blocks
    k_conv1<<<768, 256, 0, stream>>>(xb, nbr, W1T, WdT, y1b, stats);
    if (bf16y2) {
        k_conv2<true><<<1024, 128, 0, stream>>>(y1b, nbr, W2T, g1, b1,
                                                y2b, nullptr, stats);
        k_final<true><<<1024, 256, 0, stream>>>(xb, WdT, y2b, (float*)d_out, stats,
                                                g2, b2, gd, bd);
    } else {
        k_conv2<false><<<1024, 128, 0, stream>>>(y1b, nbr, W2T, g1, b1,
                                                 nullptr, (float*)d_out, stats);
        k_final<false><<<1024, 256, 0, stream>>>(xb, WdT, nullptr, (float*)d_out, stats,
                                                 g2, b2, gd, bd);
    }
}

// Round 10
// 577.839 us; speedup vs baseline: 1.6664x; 1.0233x over previous
//
#include <hip/hip_runtime.h>
#include <hip/hip_bf16.h>

#define NV 1000000
#define CI 32
#define CO 64
#define KK 9
#define NG (NV / 16)          // 62500 voxel-groups of 16 (exact)
#define EPSV 1e-5f

typedef __bf16 bf16x8 __attribute__((ext_vector_type(8)));
typedef __bf16 bf16x4 __attribute__((ext_vector_type(4)));
typedef float  f32x4  __attribute__((ext_vector_type(4)));

__device__ __forceinline__ f32x4 mfma16(bf16x8 a, bf16x8 b, f32x4 c) {
    // D[16x16] = A[16x32] * B[32x16] + C
    // A: row=lane&15, k=(lane>>4)*8+j ; B: col=lane&15, k=(lane>>4)*8+j
    // D: col=lane&15, row=(lane>>4)*4+reg   [learn_hip m89 verified]
    return __builtin_amdgcn_mfma_f32_16x16x32_bf16(a, b, c, 0, 0, 0);
}

__device__ __forceinline__ float xredseg(float v) {   // sum over lane{+16,+32}
    v += __shfl_xor(v, 16, 64);
    v += __shfl_xor(v, 32, 64);
    return v;
}

// ---------------- merged prep: x fp32->bf16 (blocks 0..15624) +
//                  weight transpose to [k][co][ci] bf16 (blocks 15625..15848) --
__global__ void k_prep(const float* __restrict__ x, __bf16* __restrict__ xb,
                       const float* __restrict__ W1, const float* __restrict__ W2,
                       const float* __restrict__ Wd,
                       __bf16* __restrict__ W1T, __bf16* __restrict__ W2T,
                       __bf16* __restrict__ WdT) {
    int bid = blockIdx.x;
    if (bid < 15625) {
        int i = bid * 256 + threadIdx.x;             // one thread per 8 elems
        const float4* px = (const float4*)x + 2 * (size_t)i;
        float4 u = px[0], v = px[1];
        bf16x8 o;
        o[0] = (__bf16)u.x; o[1] = (__bf16)u.y; o[2] = (__bf16)u.z; o[3] = (__bf16)u.w;
        o[4] = (__bf16)v.x; o[5] = (__bf16)v.y; o[6] = (__bf16)v.z; o[7] = (__bf16)v.w;
        *((bf16x8*)xb + i) = o;
    } else {
        int i = (bid - 15625) * 256 + threadIdx.x;   // 0..57343 exactly
        const int n1 = KK * CO * CI;      // 18432
        const int n2 = KK * CO * CO;      // 36864
        const int nd = CO * CI;           // 2048
        if (i < n1) {
            int k = i / (CO * CI), r = i % (CO * CI), co = r / CI, ci = r % CI;
            W1T[i] = (__bf16)W1[(k * CI + ci) * CO + co];
        } else if (i < n1 + n2) {
            int j = i - n1;
            int k = j / (CO * CO), r = j % (CO * CO), co = r / CO, ci = r % CO;
            W2T[j] = (__bf16)W2[(k * CO + ci) * CO + co];
        } else if (i < n1 + n2 + nd) {
            int j = i - n1 - n2;
            int co = j / CI, ci = j % CI;
            WdT[j] = (__bf16)Wd[ci * CO + co];
        }
    }
}

// ---------------- conv1: reg-double-buffered gather-MFMA, W1 in LDS ----------
// ROUND-8 version verbatim (measured 250.5 µs — direct 2-B nt scatter stores;
// the 240 MB WRITE inflation is free because conv1 is not write-BW-bound,
// while round-9's LDS store-staging cost +6.5 µs of critical-path latency).
__global__ __launch_bounds__(256, 2) void k_conv1(
    const __bf16* __restrict__ xb, const int* __restrict__ nbr,
    const __bf16* __restrict__ W1T, const __bf16* __restrict__ WdT,
    __bf16* __restrict__ y1b, float* __restrict__ stats) {
    __shared__ __align__(16) char w1smem[KK * CO * CI * 2];   // 36864 B

    const int lane = threadIdx.x & 63;
    const int w    = threadIdx.x >> 6;
    const int r    = lane & 15;
    const int seg  = lane >> 4;
    const int sseg = seg ^ ((r >> 1) & 3);   // W1-LDS read swizzle (2-way, free)

    // stage W1T -> LDS: 2304 16B-chunks, 256 threads x 9, SOURCE pre-swizzled
#pragma unroll
    for (int j = 0; j < 9; j++) {
        int c    = j * 256 + threadIdx.x;              // linear LDS chunk id
        int segc = c & 3;
        int rc   = (c >> 2) & 15;
        int csrc = (c & ~3) | (segc ^ ((rc >> 1) & 3));
        const __bf16* srcp = W1T + (size_t)csrc * 8;
        __builtin_amdgcn_global_load_lds(
            (const __attribute__((address_space(1))) void*)srcp,
            (__attribute__((address_space(3))) void*)(w1smem + j * 4096 + w * 1024),
            16, 0, 0);
    }
    __syncthreads();

    bf16x8 wd[4];
#pragma unroll
    for (int t = 0; t < 4; t++)
        wd[t] = *(const bf16x8*)(WdT + (size_t)(t * 16 + r) * CI + seg * 8);

    float ps1[4] = {0.f,0.f,0.f,0.f}, pq1[4] = {0.f,0.f,0.f,0.f};
    float psd[4] = {0.f,0.f,0.f,0.f}, pqd[4] = {0.f,0.f,0.f,0.f};

    const int slot   = blockIdx.x * 4 + w;
    const int stride = gridDim.x * 4;
    const f32x4 z = {0.f, 0.f, 0.f, 0.f};

    auto loadIdx = [&](int (&idx)[KK], int tile) {
        const int* nb = nbr + (size_t)(tile * 16 + r) * KK;
#pragma unroll
        for (int k = 0; k < KK; k++) idx[k] = nb[k];
    };
    auto gather9 = [&](bf16x8 (&g)[KK], const int (&idx)[KK]) {
#pragma unroll
        for (int k = 0; k < KK; k++)
            g[k] = *(const bf16x8*)(xb + (size_t)idx[k] * CI + seg * 8);
    };
    auto loadAd = [&](int tile) {
        return *(const bf16x8*)(xb + (size_t)(tile * 16 + r) * CI + seg * 8);
    };
    auto compute = [&](int tile, const bf16x8 (&g)[KK], bf16x8 ad) {
        int w1off = 0;
        asm volatile("" : "+v"(w1off));        // defeat cross-iteration hoisting
        const __bf16* wb = (const __bf16*)w1smem + w1off;

        f32x4 acc[4]  = {z, z, z, z};
        f32x4 accd[4] = {z, z, z, z};
#pragma unroll
        for (int t = 0; t < 4; t++) accd[t] = mfma16(ad, wd[t], accd[t]);
#pragma unroll
        for (int k = 0; k < KK; k++) {
#pragma unroll
            for (int t = 0; t < 4; t++) {
                bf16x8 b = *(const bf16x8*)(wb + k * 2048 + t * 512 + r * 32 + sseg * 8);
                acc[t] = mfma16(g[k], b, acc[t]);
            }
        }

        const int vb = tile * 16;
#pragma unroll
        for (int t = 0; t < 4; t++) {
#pragma unroll
            for (int rr = 0; rr < 4; rr++) {
                float val = acc[t][rr];
                int row = vb + seg * 4 + rr;
                __builtin_nontemporal_store((__bf16)val, &y1b[(size_t)row * CO + t * 16 + r]);
                ps1[t] += val; pq1[t] += val * val;
                float dv = accd[t][rr];
                psd[t] += dv; pqd[t] += dv * dv;
            }
        }
    };

    int idx0[KK], idx1[KK];
    bf16x8 g0[KK], g1[KK];
    bf16x8 ad0, ad1;

    int it = slot;                    // slot < 3072 <= NG always
    loadIdx(idx0, it);
    gather9(g0, idx0); ad0 = loadAd(it);
    int itn = it + stride;
    bool have = (itn < NG);
    if (have) loadIdx(idx1, itn);

    while (true) {
        if (have) {
            gather9(g1, idx1); ad1 = loadAd(itn);
            int it2 = itn + stride;
            if (it2 < NG) loadIdx(idx0, it2);
        }
        compute(it, g0, ad0);
        if (!have) break;
        it = itn; itn = it + stride; have = (itn < NG);

        if (have) {
            gather9(g0, idx0); ad0 = loadAd(itn);
            int it2 = itn + stride;
            if (it2 < NG) loadIdx(idx1, it2);
        }
        compute(it, g1, ad1);
        if (!have) break;
        it = itn; itn = it + stride; have = (itn < NG);
    }

#pragma unroll
    for (int t = 0; t < 4; t++) {
        ps1[t] = xredseg(ps1[t]); pq1[t] = xredseg(pq1[t]);
        psd[t] = xredseg(psd[t]); pqd[t] = xredseg(pqd[t]);
    }
    if (lane < 16) {
#pragma unroll
        for (int t = 0; t < 4; t++) {
            atomicAdd(&stats[0 * 64 + t * 16 + lane], ps1[t]);
            atomicAdd(&stats[1 * 64 + t * 16 + lane], pq1[t]);
            atomicAdd(&stats[2 * 64 + t * 16 + lane], psd[t]);
            atomicAdd(&stats[3 * 64 + t * 16 + lane], pqd[t]);
        }
    }
}

// ---------------- conv2: reg-staged gather, BN1+ReLU once at staging ----------
// ROUND-9 version verbatim: bf16 y2 via per-wave LDS staging + dense 16-B nt
// stores (BF16OUT), f32 nt scatter fallback.
#define TILE_B (16 * KK * 128)     // 18432 B per buffer

template <bool BF16OUT>
__global__ __launch_bounds__(128, 2) void k_conv2(
    const __bf16* __restrict__ h1b, const int* __restrict__ nbr,
    const __bf16* __restrict__ W2T, const float* __restrict__ g1,
    const float* __restrict__ b1,
    __bf16* __restrict__ y2b, float* __restrict__ y2f,
    float* __restrict__ stats) {
    __shared__ __align__(16) char smem[2][TILE_B];   // 36864 B
    __shared__ __align__(16) char ystage2[2][1024];  // per-wave C staging (bf16 path)

    const int lane = threadIdx.x & 63;
    const int w    = threadIdx.x >> 6;      // 0..1 = co-half
    const int r    = lane & 15;
    const int seg  = lane >> 4;
    const int p    = lane & 7;              // staging channel-chunk (static)

    bf16x8 w2[KK][2][2];                    // [k][t2][s]
#pragma unroll
    for (int k = 0; k < KK; k++)
#pragma unroll
        for (int t2 = 0; t2 < 2; t2++)
#pragma unroll
            for (int s = 0; s < 2; s++) {
                int co = w * 32 + t2 * 16 + r;
                int ci = s * 32 + seg * 8;
                w2[k][t2][s] = *(const bf16x8*)(W2T + ((size_t)(k * CO + co)) * CO + ci);
            }

    // BN1 consts for this thread's staging channels ci = p*8 .. p*8+7
    float scP[8], shP[8];
#pragma unroll
    for (int j = 0; j < 8; j++) {
        int c0 = p * 8 + j;
        float mu  = stats[c0] * (1.0f / NV);
        float var = stats[64 + c0] * (1.0f / NV) - mu * mu;
        float s   = g1[c0] * rsqrtf(var + EPSV);
        scP[j] = s; shP[j] = b1[c0] - mu * s;
    }

    // per-thread chunk constants: chunk c = w*576 + s*64 + lane
    int ri[9], dstoff[9];
#pragma unroll
    for (int s = 0; s < 9; s++) {
        int c = w * 576 + s * 64 + lane;
        int rIdx = c >> 3;
        int i = (rIdx * 57) >> 9;             // floor(rIdx/9), rIdx<512
        ri[s] = rIdx;
        dstoff[s] = rIdx * 128 + ((p ^ (i & 7)) * 16);
    }

    auto loadIdx = [&](int (&ix)[9], int tile) {
        const int* nb = nbr + (size_t)tile * (16 * KK);
#pragma unroll
        for (int s = 0; s < 9; s++) ix[s] = nb[ri[s]];
    };
    auto loadDat = [&](f32x4 (&d)[9], const int (&ix)[9]) {
#pragma unroll
        for (int s = 0; s < 9; s++)
            d[s] = *(const f32x4*)(h1b + (size_t)ix[s] * CO + p * 8);
    };
    auto xform = [&](char* tb, const f32x4 (&d)[9]) {
#pragma unroll
        for (int s = 0; s < 9; s++) {
            union { f32x4 f; bf16x8 b; } u; u.f = d[s];
            bf16x8 o;
#pragma unroll
            for (int j = 0; j < 8; j++)
                o[j] = (__bf16)fmaxf((float)u.b[j] * scP[j] + shP[j], 0.f);
            *(bf16x8*)(tb + dstoff[s]) = o;
        }
    };

    float ps[2] = {0.f, 0.f}, pq[2] = {0.f, 0.f};
    const f32x4 z = {0.f, 0.f, 0.f, 0.f};
    const int sw = r & 7;
    const int G = gridDim.x;

    int idxN[9]; f32x4 dat[9];
    int it = blockIdx.x;
    loadIdx(idxN, it);
    loadDat(dat, idxN);                                   // data(it)
    { int t1 = it + G;     loadIdx(idxN, t1 < NG ? t1 : NG - 1); }
    xform(smem[0], dat);                                  // waits data(it)
    loadDat(dat, idxN);                                   // data(it+G)
    { int t2 = it + 2 * G; loadIdx(idxN, t2 < NG ? t2 : NG - 1); }
    __syncthreads();
    int cur = 0;

    for (; it < NG; it += G) {
        // ---- compute tile `it` from smem[cur]: pure ds_read + MFMA ----
        const __bf16* base = (const __bf16*)smem[cur];
        f32x4 acc[2] = {z, z};
#pragma unroll
        for (int k = 0; k < KK; k++) {
            const __bf16* rp = base + (size_t)(r * KK + k) * 64;
            bf16x8 a0 = *(const bf16x8*)(rp + ((seg ^ sw) * 8));
            bf16x8 a1 = *(const bf16x8*)(rp + (((4 + seg) ^ sw) * 8));
            acc[0] = mfma16(a0, w2[k][0][0], acc[0]);
            acc[0] = mfma16(a1, w2[k][0][1], acc[0]);
            acc[1] = mfma16(a0, w2[k][1][0], acc[1]);
            acc[1] = mfma16(a1, w2[k][1][1], acc[1]);
        }

        const int vb = it * 16;
        if constexpr (BF16OUT) {
            // stage to per-wave LDS (key = row>>2), then dense 16-B nt stores
            char* yst = ystage2[w];
#pragma unroll
            for (int t2 = 0; t2 < 2; t2++) {
#pragma unroll
                for (int rr = 0; rr < 4; rr++) {
                    float val = acc[t2][rr];        // y2[vb+row][w*32+t2*16+r]
                    ps[t2] += val; pq[t2] += val * val;
                    int row = seg * 4 + rr;
                    int byte = row * 64 + ((t2 * 32 + 2 * r) ^ ((row >> 2) << 4));
                    *(__bf16*)(yst + byte) = (__bf16)val;
                }
            }
            {
                int row  = lane >> 2;               // chunk c = lane, 16B each
                int part = lane & 3;
                bf16x8 v = *(const bf16x8*)(yst + row * 64 + ((part ^ (row >> 2)) << 4));
                __builtin_nontemporal_store(
                    v, (bf16x8*)(y2b + (size_t)(vb + row) * CO + w * 32 + part * 8));
            }
        } else {
#pragma unroll
            for (int t2 = 0; t2 < 2; t2++) {
#pragma unroll
                for (int rr = 0; rr < 4; rr++) {
                    float val = acc[t2][rr];
                    int row = vb + seg * 4 + rr;
                    int c = w * 32 + t2 * 16 + r;
                    __builtin_nontemporal_store(val, &y2f[(size_t)row * CO + c]);
                    ps[t2] += val; pq[t2] += val * val;
                }
            }
        }

        int nx = it + G;
        if (nx < NG) {
            xform(smem[cur ^ 1], dat);                    // stage tile nx (post-BN)
            loadDat(dat, idxN);                           // issue data(it+2G)
            { int t3 = it + 3 * G; loadIdx(idxN, t3 < NG ? t3 : NG - 1); }
            __syncthreads();
            cur ^= 1;
        }
    }

#pragma unroll
    for (int t2 = 0; t2 < 2; t2++) { ps[t2] = xredseg(ps[t2]); pq[t2] = xredseg(pq[t2]); }
    if (lane < 16) {
#pragma unroll
        for (int t2 = 0; t2 < 2; t2++) {
            atomicAdd(&stats[4 * 64 + w * 32 + t2 * 16 + lane], ps[t2]);
            atomicAdd(&stats[5 * 64 + w * 32 + t2 * 16 + lane], pq[t2]);
        }
    }
}

// ---------------- final: out = relu(BN2(y2) + BNd(xb@WdT)) ----------------
// ROUND-9 version verbatim: BF16IN reads y2 as bf16; fallback f32 in place.
template <bool BF16IN>
__global__ __launch_bounds__(256, 2) void k_final(
    const __bf16* __restrict__ xb, const __bf16* __restrict__ WdT,
    const __bf16* __restrict__ y2b,
    float* __restrict__ out, const float* __restrict__ stats,
    const float* __restrict__ g2, const float* __restrict__ b2,
    const float* __restrict__ gd, const float* __restrict__ bd) {
    __shared__ float s2[CO], sh2[CO], sdv[CO], shd[CO];
    int t = threadIdx.x;
    if (t < CO) {
        float mu2  = stats[4 * 64 + t] * (1.0f / NV);
        float var2 = stats[5 * 64 + t] * (1.0f / NV) - mu2 * mu2;
        float s = g2[t] * rsqrtf(var2 + EPSV);
        s2[t] = s; sh2[t] = b2[t] - mu2 * s;
        float mud  = stats[2 * 64 + t] * (1.0f / NV);
        float vard = stats[3 * 64 + t] * (1.0f / NV) - mud * mud;
        float sd = gd[t] * rsqrtf(vard + EPSV);
        sdv[t] = sd; shd[t] = bd[t] - mud * sd;
    }
    __syncthreads();

    const int lane = threadIdx.x & 63;
    const int w    = threadIdx.x >> 6;
    const int r    = lane & 15;
    const int seg  = lane >> 4;

    bf16x8 wd[4];
#pragma unroll
    for (int t4 = 0; t4 < 4; t4++)
        wd[t4] = *(const bf16x8*)(WdT + (size_t)(t4 * 16 + r) * CI + seg * 8);

    const int slot = blockIdx.x * 4 + w;
    const int nslots = gridDim.x * 4;
    const f32x4 z = {0.f, 0.f, 0.f, 0.f};

    for (int gid = slot; gid < NG; gid += nslots) {
        const int vb = gid * 16;
        const int v  = vb + r;
        bf16x8 ad = *(const bf16x8*)(xb + (size_t)v * CI + seg * 8);
        f32x4 accd[4] = {z, z, z, z};
#pragma unroll
        for (int t4 = 0; t4 < 4; t4++) accd[t4] = mfma16(ad, wd[t4], accd[t4]);
#pragma unroll
        for (int t4 = 0; t4 < 4; t4++) {
#pragma unroll
            for (int rr = 0; rr < 4; rr++) {
                int row = vb + seg * 4 + rr;
                int c = t4 * 16 + r;
                size_t o = (size_t)row * CO + c;
                float y2v;
                if constexpr (BF16IN) y2v = (float)y2b[o];
                else                  y2v = out[o];
                float res = s2[c] * y2v + sh2[c] + sdv[c] * accd[t4][rr] + shd[c];
                __builtin_nontemporal_store(fmaxf(res, 0.f), &out[o]);
            }
        }
    }
}

extern "C" void kernel_launch(void* const* d_in, const int* in_sizes, int n_in,
                              void* d_out, int out_size, void* d_ws, size_t ws_size,
                              hipStream_t stream) {
    const float* x  = (const float*)d_in[0];
    const float* W1 = (const float*)d_in[1];
    const float* g1 = (const float*)d_in[2];
    const float* b1 = (const float*)d_in[3];
    const float* W2 = (const float*)d_in[4];
    const float* g2 = (const float*)d_in[5];
    const float* b2 = (const float*)d_in[6];
    const float* Wd = (const float*)d_in[7];
    const float* gd = (const float*)d_in[8];
    const float* bd = (const float*)d_in[9];
    const int*  nbr = (const int*)d_in[10];

    char* ws = (char*)d_ws;
    __bf16* xb  = (__bf16*)ws;                              // 64,000,000 B
    __bf16* y1b = (__bf16*)(ws + 64000000);                 // 128,000,000 B
    __bf16* W1T = (__bf16*)(ws + 192000000);                // 36,864 B
    __bf16* W2T = W1T + KK * CO * CI;                       // 73,728 B
    __bf16* WdT = W2T + KK * CO * CO;                       // 4,096 B
    float* stats = (float*)(ws + 192000000 + 2 * (KK*CO*CI + KK*CO*CO + CO*CI));
    // y2 bf16 buffer (if workspace allows): after stats, 256B-aligned
    size_t y2off = ((192000000 + 2 * (KK*CO*CI + KK*CO*CO + CO*CI) + 6*64*4) + 255) & ~(size_t)255;
    __bf16* y2b = (__bf16*)(ws + y2off);
    bool bf16y2 = (ws_size >= y2off + (size_t)NV * CO * 2 + 256);

    hipMemsetAsync(stats, 0, 6 * 64 * sizeof(float), stream);

    // merged prep: 15625 x-conversion blocks + 224 weight-transpose blocks
    k_prep<<<15625 + 224, 256, 0, stream>>>(x, xb, W1, W2, Wd, W1T, W2T, WdT);
    k_conv1<<<768, 256, 0, stream>>>(xb, nbr, W1T, WdT, y1b, stats);
    if (bf16y2) {
        k_conv2<true><<<1024, 128, 0, stream>>>(y1b, nbr, W2T, g1, b1,
                                                y2b, nullptr, stats);
        k_final<true><<<1024, 256, 0, stream>>>(xb, WdT, y2b, (float*)d_out, stats,
                                                g2, b2, gd, bd);
    } else {
        k_conv2<false><<<1024, 128, 0, stream>>>(y1b, nbr, W2T, g1, b1,
                                                 nullptr, (float*)d_out, stats);
        k_final<false><<<1024, 256, 0, stream>>>(xb, WdT, nullptr, (float*)d_out, stats,
                                                 g2, b2, gd, bd);
    }
}